// Round 5
// baseline (83.928 us; speedup 1.0000x reference)
//
#include <hip/hip_runtime.h>
#include <math.h>

#define TLEN 1024

typedef int   i32x2 __attribute__((ext_vector_type(2)));
typedef float v2f   __attribute__((ext_vector_type(2)));

__device__ __forceinline__ v2f vswap(v2f a){ return __builtin_shufflevector(a, a, 1, 0); }
// complex multiply by split-form twiddle: xx=(c,c), myx=(-s,s); z*w
__device__ __forceinline__ v2f cmul_sp(v2f z, v2f xx, v2f myx){
    return __builtin_elementwise_fma(xx, z, myx * vswap(z));
}
__device__ __forceinline__ v2f cmulnegi(v2f a){ return (v2f){a.y, -a.x}; } // a * (-i)
__device__ __forceinline__ int bitrev6(int l){
    return ((l & 1) << 5) | ((l & 2) << 3) | ((l & 4) << 1)
         | ((l & 8) >> 1) | ((l & 16) >> 3) | ((l & 32) >> 5);
}

// ---- cross-lane partner primitives (32-bit per component) ----
#define DPP_XOR1  0xB1   // quad_perm [1,0,3,2]
#define DPP_XOR2  0x4E   // quad_perm [2,3,0,1]
#define DPP_XOR8  0x128  // row_ror:8
#define SWZ_XOR4  0x101F // bitmode xor=4
#define SWZ_XOR16 0x401F // bitmode xor=16

template<int CTRL>
__device__ __forceinline__ v2f dpp2v(v2f v){
    return (v2f){
        __int_as_float(__builtin_amdgcn_mov_dpp(__float_as_int(v.x), CTRL, 0xF, 0xF, false)),
        __int_as_float(__builtin_amdgcn_mov_dpp(__float_as_int(v.y), CTRL, 0xF, 0xF, false))};
}
template<int PAT>
__device__ __forceinline__ v2f swz2v(v2f v){
    return (v2f){
        __int_as_float(__builtin_amdgcn_ds_swizzle(__float_as_int(v.x), PAT)),
        __int_as_float(__builtin_amdgcn_ds_swizzle(__float_as_int(v.y), PAT))};
}
__device__ __forceinline__ float p32f(float v, bool up){
#if __has_builtin(__builtin_amdgcn_permlane32_swap)
    i32x2 r = __builtin_amdgcn_permlane32_swap(__float_as_int(v), __float_as_int(v), false, false);
    return __int_as_float(up ? r[0] : r[1]);
#else
    int a = __float_as_int(v), b = __float_as_int(v);
    asm("v_permlane32_swap_b32 %0, %1" : "+v"(a), "+v"(b));
    return __int_as_float(up ? a : b);
#endif
}
__device__ __forceinline__ v2f p32v(v2f v, bool up){
    return (v2f){p32f(v.x, up), p32f(v.y, up)};
}

// DFT-4 (radix-2x2), packed
__device__ __forceinline__ void dft4v(v2f x0, v2f x1, v2f x2, v2f x3,
                                      v2f& y0, v2f& y1, v2f& y2, v2f& y3){
    v2f t0 = x0 + x2, t1 = x0 - x2, t2 = x1 + x3, t3 = x1 - x3;
    v2f n3 = cmulnegi(t3);
    y0 = t0 + t2;  y2 = t0 - t2;
    y1 = t1 + n3;  y3 = t1 - n3;
}

// in-lane 16-point DFT, natural in -> natural out, packed split-form twiddles
__device__ __forceinline__ void fft16v(v2f z[16]){
    const float C1 = 0.92387953251128675613f, S1 = 0.38268343236508977173f;
    const float H  = 0.70710678118654752440f;
    const v2f XX1 = { C1,  C1}, MYX1 = { S1, -S1};   // W16^1 = C1 - iS1
    const v2f XX2 = {  H,   H}, MYX2 = {  H,  -H};   // W16^2
    const v2f XX3 = { S1,  S1}, MYX3 = { C1, -C1};   // W16^3
    const v2f XX6 = { -H,  -H}, MYX6 = {  H,  -H};   // W16^6
    const v2f XX9 = {-C1, -C1}, MYX9 = {-S1,  S1};   // W16^9

    v2f A0[4], A1[4], A2[4], A3[4];
    #pragma unroll
    for (int b = 0; b < 4; ++b)
        dft4v(z[b], z[4+b], z[8+b], z[12+b], A0[b], A1[b], A2[b], A3[b]);

    A1[1] = cmul_sp(A1[1], XX1, MYX1);  A1[2] = cmul_sp(A1[2], XX2, MYX2);  A1[3] = cmul_sp(A1[3], XX3, MYX3);
    A2[1] = cmul_sp(A2[1], XX2, MYX2);  A2[2] = cmulnegi(A2[2]);            A2[3] = cmul_sp(A2[3], XX6, MYX6);
    A3[1] = cmul_sp(A3[1], XX3, MYX3);  A3[2] = cmul_sp(A3[2], XX6, MYX6);  A3[3] = cmul_sp(A3[3], XX9, MYX9);

    dft4v(A0[0], A0[1], A0[2], A0[3], z[0], z[4], z[8],  z[12]);
    dft4v(A1[0], A1[1], A1[2], A1[3], z[1], z[5], z[9],  z[13]);
    dft4v(A2[0], A2[1], A2[2], A2[3], z[2], z[6], z[10], z[14]);
    dft4v(A3[0], A3[1], A3[2], A3[3], z[3], z[7], z[11], z[15]);
}

// DIF stage (twiddled): o=partner(z); pre=fma(sg,z,o); z=pre*w (w=identity on lower lanes)
template<bool TW, typename F>
__device__ __forceinline__ void dif_stage(v2f z[16], F partner, v2f sgv, v2f xx, v2f myx){
    #pragma unroll
    for (int r = 0; r < 16; ++r){
        v2f o = partner(z[r]);
        v2f pre = __builtin_elementwise_fma(sgv, z[r], o);
        z[r] = TW ? cmul_sp(pre, xx, myx) : pre;
    }
}
template<bool TW, typename F>
__device__ __forceinline__ void dit_stage(v2f z[16], F partner, v2f sgv, v2f xx, v2f myx){
    #pragma unroll
    for (int r = 0; r < 16; ++r){
        v2f zz = TW ? cmul_sp(z[r], xx, myx) : z[r];
        v2f o = partner(zz);
        z[r] = __builtin_elementwise_fma(sgv, zz, o);
    }
}

// cross-lane DIF FFT-64: natural in -> bit-reversed out
__device__ __forceinline__ void xfft_dif(v2f z[16], const v2f Wxx[5], const v2f Wmyx[5], int lane){
    const v2f Z0 = {0.0f, 0.0f};
    {   const bool up = (lane & 32) != 0; v2f sg = {up?-1.0f:1.0f, up?-1.0f:1.0f};
        dif_stage<true>(z, [&](v2f v){ return p32v(v, up); }, sg, Wxx[4], Wmyx[4]); }
    {   const bool up = (lane & 16) != 0; v2f sg = {up?-1.0f:1.0f, up?-1.0f:1.0f};
        dif_stage<true>(z, [](v2f v){ return swz2v<SWZ_XOR16>(v); }, sg, Wxx[3], Wmyx[3]); }
    {   const bool up = (lane & 8) != 0;  v2f sg = {up?-1.0f:1.0f, up?-1.0f:1.0f};
        dif_stage<true>(z, [](v2f v){ return dpp2v<DPP_XOR8>(v); }, sg, Wxx[2], Wmyx[2]); }
    {   const bool up = (lane & 4) != 0;  v2f sg = {up?-1.0f:1.0f, up?-1.0f:1.0f};
        dif_stage<true>(z, [](v2f v){ return swz2v<SWZ_XOR4>(v); }, sg, Wxx[1], Wmyx[1]); }
    {   const bool up = (lane & 2) != 0;  v2f sg = {up?-1.0f:1.0f, up?-1.0f:1.0f};
        dif_stage<true>(z, [](v2f v){ return dpp2v<DPP_XOR2>(v); }, sg, Wxx[0], Wmyx[0]); }
    {   const bool up = (lane & 1) != 0;  v2f sg = {up?-1.0f:1.0f, up?-1.0f:1.0f};
        dif_stage<false>(z, [](v2f v){ return dpp2v<DPP_XOR1>(v); }, sg, Z0, Z0); }
}

// cross-lane DIT FFT-64: bit-reversed in -> natural out
__device__ __forceinline__ void xfft_dit(v2f z[16], const v2f Wxx[5], const v2f Wmyx[5], int lane){
    const v2f Z0 = {0.0f, 0.0f};
    {   const bool up = (lane & 1) != 0;  v2f sg = {up?-1.0f:1.0f, up?-1.0f:1.0f};
        dit_stage<false>(z, [](v2f v){ return dpp2v<DPP_XOR1>(v); }, sg, Z0, Z0); }
    {   const bool up = (lane & 2) != 0;  v2f sg = {up?-1.0f:1.0f, up?-1.0f:1.0f};
        dit_stage<true>(z, [](v2f v){ return dpp2v<DPP_XOR2>(v); }, sg, Wxx[0], Wmyx[0]); }
    {   const bool up = (lane & 4) != 0;  v2f sg = {up?-1.0f:1.0f, up?-1.0f:1.0f};
        dit_stage<true>(z, [](v2f v){ return swz2v<SWZ_XOR4>(v); }, sg, Wxx[1], Wmyx[1]); }
    {   const bool up = (lane & 8) != 0;  v2f sg = {up?-1.0f:1.0f, up?-1.0f:1.0f};
        dit_stage<true>(z, [](v2f v){ return dpp2v<DPP_XOR8>(v); }, sg, Wxx[2], Wmyx[2]); }
    {   const bool up = (lane & 16) != 0; v2f sg = {up?-1.0f:1.0f, up?-1.0f:1.0f};
        dit_stage<true>(z, [](v2f v){ return swz2v<SWZ_XOR16>(v); }, sg, Wxx[3], Wmyx[3]); }
    {   const bool up = (lane & 32) != 0; v2f sg = {up?-1.0f:1.0f, up?-1.0f:1.0f};
        dit_stage<true>(z, [&](v2f v){ return p32v(v, up); }, sg, Wxx[4], Wmyx[4]); }
}

// tab layout (float4 split form (c, c, -s, s)):
//   [0 .. 6*TLEN)      exp(i*W[l][t])
//   [6*TLEN .. 7*TLEN) wmid[lane][r] = exp(-2pi*i*bitrev6(lane)*r/1024)
__global__ void tab_kernel(const float* __restrict__ W, float4* __restrict__ tab){
    int i = blockIdx.x * 256 + threadIdx.x;
    if (i < 6 * TLEN){
        float sv, cv; sincosf(W[i], &sv, &cv);
        tab[i] = make_float4(cv, cv, -sv, sv);
    } else if (i < 7 * TLEN){
        int j = i - 6 * TLEN;
        int l = j >> 4, r = j & 15;
        int cb = bitrev6(l);
        float sv, cv;
        sincosf(-6.28318530717958647692f * (float)(cb * r) / 1024.0f, &sv, &cv);
        tab[i] = make_float4(cv, cv, -sv, sv);
    }
}

template<bool TAB>
__global__ __launch_bounds__(256, 4)
void phasor_kernel(const float* __restrict__ X,
                   const float* __restrict__ W,
                   const float4* __restrict__ tab,
                   float* __restrict__ out)
{
    const int lane = threadIdx.x & 63;
    const int row  = blockIdx.x * 4 + (threadIdx.x >> 6);
    const int c = bitrev6(lane);

    // stage twiddles, split form, up-select pre-folded (identity on lower lanes)
    v2f Wxx[5], Wmyx[5];
    #pragma unroll
    for (int k = 0; k < 5; ++k){
        const int h = 2 << k;
        if (lane & h){
            float sv, cv;
            sincosf(-3.14159265358979323846f * (float)(lane & (h - 1)) / (float)h, &sv, &cv);
            Wxx[k] = (v2f){cv, cv};  Wmyx[k] = (v2f){-sv, sv};
        } else {
            Wxx[k] = (v2f){1.0f, 1.0f};  Wmyx[k] = (v2f){0.0f, 0.0f};
        }
    }
    const float theta = -6.28318530717958647692f * (float)c / 1024.0f;

    // load + encode: z = (sqrt(1-x^2), x), layout t = 16*lane + r
    v2f z[16];
    {
        const float4* px = (const float4*)(X + (size_t)row * TLEN + lane * 16);
        #pragma unroll
        for (int i = 0; i < 4; ++i){
            float4 v = px[i];
            float xs[4] = {v.x, v.y, v.z, v.w};
            #pragma unroll
            for (int j = 0; j < 4; ++j){
                float x = fminf(fmaxf(xs[j], -0.999f), 0.999f);
                z[4*i + j] = (v2f){sqrtf(fmaf(-x, x, 1.0f)), x};
            }
        }
    }

    // all positive real scales dropped — angle-invariant.

    auto midtw = [&](){
        if constexpr (TAB){
            const float4* p = tab + 6 * TLEN + lane * 16;
            #pragma unroll
            for (int r = 0; r < 16; ++r){
                float4 v = p[r];
                z[r] = cmul_sp(z[r], (v2f){v.x, v.y}, (v2f){v.z, v.w});
            }
        } else {
            #pragma unroll
            for (int r = 0; r < 16; ++r){
                float sv, cv; __sincosf(theta * (float)r, &sv, &cv);
                z[r] = cmul_sp(z[r], (v2f){cv, cv}, (v2f){-sv, sv});
            }
        }
    };

    auto even_layer = [&](int l){
        if constexpr (TAB){
            const float4* p = tab + l * TLEN + lane * 16;
            #pragma unroll
            for (int r = 0; r < 16; ++r){
                float4 v = p[r];
                z[r] = cmul_sp(z[r], (v2f){v.x, v.y}, (v2f){v.z, v.w});
            }
        } else {
            const float4* p = (const float4*)(W + l * TLEN + lane * 16);
            #pragma unroll
            for (int i = 0; i < 4; ++i){
                float4 v = p[i];
                float ws[4] = {v.x, v.y, v.z, v.w};
                #pragma unroll
                for (int j = 0; j < 4; ++j){
                    float sv, cv; __sincosf(ws[j], &sv, &cv);
                    z[4*i + j] = cmul_sp(z[4*i + j], (v2f){cv, cv}, (v2f){-sv, sv});
                }
            }
        }
        // mix: adjacent registers
        #pragma unroll
        for (int m = 0; m < 8; ++m){
            v2f a = z[2*m], b = z[2*m+1];
            z[2*m]   = a + b;
            z[2*m+1] = a - b;
        }
        xfft_dif(z, Wxx, Wmyx, lane);
        midtw();
        fft16v(z);
        // layout now strided-bitrev: reg r holds t = 64*r + c
    };

    auto odd_layer = [&](int l){
        if constexpr (TAB){
            const float4* p = tab + l * TLEN + c;
            #pragma unroll
            for (int r = 0; r < 16; ++r){
                float4 v = p[r << 6];
                z[r] = cmul_sp(z[r], (v2f){v.x, v.y}, (v2f){v.z, v.w});
            }
        } else {
            const float* p = W + l * TLEN + c;
            #pragma unroll
            for (int r = 0; r < 16; ++r){
                float sv, cv; __sincosf(p[r << 6], &sv, &cv);
                z[r] = cmul_sp(z[r], (v2f){cv, cv}, (v2f){-sv, sv});
            }
        }
        // mix: partner lane^32 (t parity = lane bit5)
        const bool upm = (lane & 32) != 0;
        const v2f sgm = {upm ? -1.0f : 1.0f, upm ? -1.0f : 1.0f};
        #pragma unroll
        for (int r = 0; r < 16; ++r){
            v2f o = p32v(z[r], upm);
            z[r] = __builtin_elementwise_fma(sgm, z[r], o);
        }
        fft16v(z);
        midtw();
        xfft_dit(z, Wxx, Wmyx, lane);
        // layout back to consecutive
    };

    even_layer(0); odd_layer(1);
    even_layer(2); odd_layer(3);
    even_layer(4);

    // ---- layer 5 shortcut: Z0 ∝ Σ_{even t} z_t * exp(i*w5[t]).
    // strided-bitrev layout: even t <=> lanes 0..31.
    {
        if constexpr (TAB){
            const float4* p = tab + 5 * TLEN + c;
            #pragma unroll
            for (int r = 0; r < 16; ++r){
                float4 v = p[r << 6];
                z[r] = cmul_sp(z[r], (v2f){v.x, v.y}, (v2f){v.z, v.w});
            }
        } else {
            const float* p = W + 5 * TLEN + c;
            #pragma unroll
            for (int r = 0; r < 16; ++r){
                float sv, cv; __sincosf(p[r << 6], &sv, &cv);
                z[r] = cmul_sp(z[r], (v2f){cv, cv}, (v2f){-sv, sv});
            }
        }
        v2f s = z[0];
        #pragma unroll
        for (int r = 1; r < 16; ++r) s = s + z[r];
        // reduce lanes 0..31 (no primitive crosses the 32-lane halves)
        s = s + dpp2v<DPP_XOR1>(s);
        s = s + dpp2v<DPP_XOR2>(s);
        s = s + swz2v<SWZ_XOR4>(s);
        s = s + dpp2v<DPP_XOR8>(s);
        s = s + swz2v<SWZ_XOR16>(s);
        if (lane == 0){
            out[row] = fmaf(s.y * rsqrtf(fmaf(s.x, s.x, s.y * s.y)), 0.5f, 0.5f);
        }
    }
}

extern "C" void kernel_launch(void* const* d_in, const int* in_sizes, int n_in,
                              void* d_out, int out_size, void* d_ws, size_t ws_size,
                              hipStream_t stream) {
    const float* X = (const float*)d_in[0];   // [4096, 1024]
    const float* W = (const float*)d_in[1];   // [6*1024]
    float* out = (float*)d_out;               // [4096]
    (void)in_sizes; (void)n_in; (void)out_size;

    const size_t need = (size_t)7 * TLEN * sizeof(float4);  // 114688 B
    if (d_ws && ws_size >= need){
        float4* tab = (float4*)d_ws;
        tab_kernel<<<(7 * TLEN + 255) / 256, 256, 0, stream>>>(W, tab);
        phasor_kernel<true><<<4096 / 4, 256, 0, stream>>>(X, W, tab, out);
    } else {
        phasor_kernel<false><<<4096 / 4, 256, 0, stream>>>(X, W, nullptr, out);
    }
}

// Round 6
// 26.382 us; speedup vs baseline: 3.1812x; 3.1812x over previous
//
#include <hip/hip_runtime.h>
#include <math.h>

#define TLEN 1024
#define PREP_T 512

typedef int i32x2 __attribute__((ext_vector_type(2)));

__device__ __forceinline__ float2 cadd(float2 a, float2 b){ return make_float2(a.x+b.x, a.y+b.y); }
__device__ __forceinline__ float2 cmul(float2 a, float2 b){
    return make_float2(fmaf(a.x, b.x, -(a.y*b.y)), fmaf(a.x, b.y, a.y*b.x));
}

// ---- cross-lane primitives (verified R4) ----
#define DPP_XOR1  0xB1   // quad_perm [1,0,3,2]
#define DPP_XOR2  0x4E   // quad_perm [2,3,0,1]
#define DPP_XOR8  0x128  // row_ror:8
#define SWZ_XOR4  0x101F // bitmode xor=4
#define SWZ_XOR16 0x401F // bitmode xor=16

template<int CTRL>
__device__ __forceinline__ float2 dpp2(float2 v){
    return make_float2(
        __int_as_float(__builtin_amdgcn_mov_dpp(__float_as_int(v.x), CTRL, 0xF, 0xF, false)),
        __int_as_float(__builtin_amdgcn_mov_dpp(__float_as_int(v.y), CTRL, 0xF, 0xF, false)));
}
template<int PAT>
__device__ __forceinline__ float2 swz2(float2 v){
    return make_float2(
        __int_as_float(__builtin_amdgcn_ds_swizzle(__float_as_int(v.x), PAT)),
        __int_as_float(__builtin_amdgcn_ds_swizzle(__float_as_int(v.y), PAT)));
}
__device__ __forceinline__ float p32f(float v, bool up){
#if __has_builtin(__builtin_amdgcn_permlane32_swap)
    i32x2 r = __builtin_amdgcn_permlane32_swap(__float_as_int(v), __float_as_int(v), false, false);
    return __int_as_float(up ? r[0] : r[1]);
#else
    int a = __float_as_int(v), b = __float_as_int(v);
    asm("v_permlane32_swap_b32 %0, %1" : "+v"(a), "+v"(b));
    return __int_as_float(up ? a : b);
#endif
}
__device__ __forceinline__ float2 p32_2(float2 v, bool up){
    return make_float2(p32f(v.x, up), p32f(v.y, up));
}

// ============================================================================
// prep: a = (D_0 M F)(D_1 M F)...(D_5 M F) e_0   (weights-only, one block)
// Layer op of the circuit is z -> F M D_l z (all symmetric), and we need
// out = e_0^T z_final = a . z_enc. Stockham FFT verified in R0.
// ============================================================================
__global__ __launch_bounds__(PREP_T)
void prep_kernel(const float* __restrict__ W, float2* __restrict__ a_out)
{
    __shared__ float2 bufA[TLEN];
    __shared__ float2 bufB[TLEN];
    __shared__ float2 twid[TLEN];   // 1023 used

    const int tid = threadIdx.x;

    // twiddles: entry e: ep=e+1, s=floor(log2 ep), Ns=2^s, j=ep-Ns -> exp(-i*pi*j/Ns)
    for (int e = tid; e < TLEN - 1; e += PREP_T){
        int ep = e + 1;
        int s  = 31 - __clz(ep);
        int Ns = 1 << s;
        int j  = ep - Ns;
        float sv, cv;
        sincosf(-3.14159265358979323846f * (float)j / (float)Ns, &sv, &cv);
        twid[e] = make_float2(cv, sv);
    }
    // v = e_0
    for (int t = tid; t < TLEN; t += PREP_T)
        bufA[t] = make_float2(t == 0 ? 1.0f : 0.0f, 0.0f);
    __syncthreads();

    const float SC = 0.02209708691207961f;  // (1/sqrt(2)) * (1/sqrt(1024))

    for (int l = 5; l >= 0; --l){
        // ---- v = F v  (Stockham radix-2, 10 stages, ends in bufA) ----
        float2* src = bufA;
        float2* dst = bufB;
        #pragma unroll
        for (int s = 0; s < 10; ++s){
            const int Ns = 1 << s;
            const int j  = tid;
            const int jm = j & (Ns - 1);
            float2 w = twid[Ns - 1 + jm];
            float2 va = src[j];
            float2 vb = src[j + PREP_T];
            float2 tb = make_float2(vb.x * w.x - vb.y * w.y,
                                    vb.x * w.y + vb.y * w.x);
            int idxD = ((j >> s) << (s + 1)) + jm;
            dst[idxD]      = make_float2(va.x + tb.x, va.y + tb.y);
            dst[idxD + Ns] = make_float2(va.x - tb.x, va.y - tb.y);
            __syncthreads();
            float2* t = src; src = dst; dst = t;
        }
        // ---- v = D_l (M v):  mix pairs (with unitary scales) then shift ----
        {
            int t0 = 2 * tid, t1 = t0 + 1;
            float2 va = bufA[t0], vb = bufA[t1];
            float2 m0 = make_float2((va.x + vb.x) * SC, (va.y + vb.y) * SC);
            float2 m1 = make_float2((va.x - vb.x) * SC, (va.y - vb.y) * SC);
            float s0, c0, s1, c1;
            sincosf(W[l * TLEN + t0], &s0, &c0);
            sincosf(W[l * TLEN + t1], &s1, &c1);
            bufA[t0] = cmul(m0, make_float2(c0, s0));
            bufA[t1] = cmul(m1, make_float2(c1, s1));
        }
        __syncthreads();
    }

    for (int t = tid; t < TLEN; t += PREP_T) a_out[t] = bufA[t];
}

// ============================================================================
// dot: out[row] = (sin(angle(a . z_row)) + 1)/2,  z_t = (sqrt(1-x^2), x)
// one wave per row, 16 elements per lane, memory-bound.
// ============================================================================
__global__ __launch_bounds__(256)
void dot_kernel(const float* __restrict__ X,
                const float2* __restrict__ a,
                float* __restrict__ out)
{
    const int lane = threadIdx.x & 63;
    const int row  = blockIdx.x * 4 + (threadIdx.x >> 6);

    const float4* px = (const float4*)(X + (size_t)row * TLEN + lane * 16);
    const float4* pa = (const float4*)(a + lane * 16);   // 16 float2 = 8 float4

    float re = 0.0f, im = 0.0f;
    #pragma unroll
    for (int i = 0; i < 4; ++i){
        float4 xv = px[i];
        float4 qa = pa[2*i];
        float4 qb = pa[2*i + 1];
        float xs[4] = {xv.x, xv.y, xv.z, xv.w};
        float ar[4] = {qa.x, qa.z, qb.x, qb.z};
        float ai[4] = {qa.y, qa.w, qb.y, qb.w};
        #pragma unroll
        for (int j = 0; j < 4; ++j){
            float x  = fminf(fmaxf(xs[j], -0.999f), 0.999f);
            float cc = sqrtf(fmaf(-x, x, 1.0f));
            // a_t * z_t, z_t = (cc, x)
            re = fmaf(ar[j], cc, re);  re = fmaf(-ai[j], x,  re);
            im = fmaf(ar[j], x,  im);  im = fmaf( ai[j], cc, im);
        }
    }

    // 64-lane complex reduce
    float2 s = make_float2(re, im);
    s = cadd(s, dpp2<DPP_XOR1>(s));
    s = cadd(s, dpp2<DPP_XOR2>(s));
    s = cadd(s, swz2<SWZ_XOR4>(s));
    s = cadd(s, dpp2<DPP_XOR8>(s));
    s = cadd(s, swz2<SWZ_XOR16>(s));
    s = cadd(s, p32_2(s, (lane & 32) != 0));

    if (lane == 0){
        out[row] = fmaf(s.y * rsqrtf(fmaf(s.x, s.x, s.y * s.y)), 0.5f, 0.5f);
    }
}

extern "C" void kernel_launch(void* const* d_in, const int* in_sizes, int n_in,
                              void* d_out, int out_size, void* d_ws, size_t ws_size,
                              hipStream_t stream) {
    const float* X = (const float*)d_in[0];   // [4096, 1024]
    const float* W = (const float*)d_in[1];   // [6*1024]
    float* out = (float*)d_out;               // [4096]
    (void)in_sizes; (void)n_in; (void)out_size; (void)ws_size;

    float2* aW = (float2*)d_ws;               // 8 KiB of the >=114 KiB workspace

    prep_kernel<<<1, PREP_T, 0, stream>>>(W, aW);
    dot_kernel<<<4096 / 4, 256, 0, stream>>>(X, aW, out);
}